// Round 1
// baseline (25938.284 us; speedup 1.0000x reference)
//
#include <hip/hip_runtime.h>
#include <hip/hip_cooperative_groups.h>
#include <hip/hip_fp16.h>

namespace cg = cooperative_groups;

#define N_INP 256
#define NH    2048
#define NOUT  256
#define BB    64
#define TT    512

typedef __bf16 bf16x8 __attribute__((ext_vector_type(8)));
typedef float  f32x4  __attribute__((ext_vector_type(4)));

__device__ __forceinline__ unsigned short f2bf(float f) {
  unsigned u = __float_as_uint(f);
  u += 0x7fffu + ((u >> 16) & 1u);          // RTNE
  return (unsigned short)(u >> 16);
}

__device__ __forceinline__ float fast_tanh(float x) {
  x = fminf(9.0f, fmaxf(-9.0f, x));
  float e = __expf(2.0f * x);
  return (e - 1.0f) / (e + 1.0f);
}

__device__ __forceinline__ f32x4 mfma16(uint4 a, uint4 b, f32x4 c) {
  return __builtin_amdgcn_mfma_f32_16x16x32_bf16(
      __builtin_bit_cast(bf16x8, a), __builtin_bit_cast(bf16x8, b), c, 0, 0, 0);
}

// ---------------- prep: u (B,T,256) f32 -> ut (T*B, 256) bf16 ----------------
__global__ void k_ut(const float* __restrict__ u, unsigned short* __restrict__ ut) {
  int idx = blockIdx.x * 256 + threadIdx.x;    // over 64*512*64 float4 units
  int k4 = idx & 63;
  int rowbt = idx >> 6;                        // row = t*64+b
  int t = rowbt >> 6, b = rowbt & 63;
  float4 f = *(const float4*)(u + ((size_t)b * TT + t) * N_INP + k4 * 4);
  uint2 pk;
  pk.x = f2bf(f.x) | ((unsigned)f2bf(f.y) << 16);
  pk.y = f2bf(f.z) | ((unsigned)f2bf(f.w) << 16);
  *(uint2*)(ut + (size_t)rowbt * N_INP + k4 * 4) = pk;
}

// ------------- prep: W (K,N) f32 row-major -> B-fragment-ordered bf16 --------
// Wf layout: [kb][nt][lane][8], blockIdx.x = kb*(N/16)+nt
__global__ void k_swz(const float* __restrict__ W, unsigned short* __restrict__ Wf, int N) {
  int lane = threadIdx.x;
  int nt16 = N >> 4;
  int kb = blockIdx.x / nt16;
  int nt = blockIdx.x - kb * nt16;
  int k0 = kb * 32 + ((lane >> 4) << 3);
  int c  = nt * 16 + (lane & 15);
  unsigned short v[8];
#pragma unroll
  for (int j = 0; j < 8; ++j) v[j] = f2bf(W[(size_t)(k0 + j) * N + c]);
  uint4 p;
  p.x = v[0] | ((unsigned)v[1] << 16);
  p.y = v[2] | ((unsigned)v[3] << 16);
  p.z = v[4] | ((unsigned)v[5] << 16);
  p.w = v[6] | ((unsigned)v[7] << 16);
  ((uint4*)Wf)[(size_t)blockIdx.x * 64 + lane] = p;
}

// ---------------- persistent recurrence kernel (cooperative) -----------------
// 256 WGs x 128 threads. WG (cg,bh): columns [cg*16,cg*16+16), batches [bh*32,bh*32+32).
// W_hh column slice resident in LDS (fragment order) for all 512 steps.
__global__ __launch_bounds__(128) void k_step(
    const float* __restrict__ Whh, const float* __restrict__ Wuh,
    const float* __restrict__ b_h, const float* __restrict__ tau,
    const float* __restrict__ h0, const unsigned short* __restrict__ ut,
    unsigned short* __restrict__ H) {
  __shared__ unsigned short lds[64 * 64 * 8];     // 65536 B: [kb][lane][8]
  const int wg = blockIdx.x;
  const int cgp = wg >> 1;          // colgroup 0..127
  const int bhh = wg & 1;           // batch half
  const int tid = threadIdx.x;
  const int wave = tid >> 6;        // m-tile within batch half
  const int lane = tid & 63;
  const int q = lane >> 4, p = lane & 15;

  // one-time: stage W_hh slice into LDS in B-fragment order
  for (int s = tid; s < 64 * 64; s += 128) {
    int kb = s >> 6, l = s & 63;
    int k0 = kb * 32 + ((l >> 4) << 3);
    int c = cgp * 16 + (l & 15);
    unsigned short v[8];
#pragma unroll
    for (int j = 0; j < 8; ++j) v[j] = f2bf(Whh[(size_t)(k0 + j) * NH + c]);
    uint4 pk;
    pk.x = v[0] | ((unsigned)v[1] << 16);
    pk.y = v[2] | ((unsigned)v[3] << 16);
    pk.z = v[4] | ((unsigned)v[5] << 16);
    pk.w = v[6] | ((unsigned)v[7] << 16);
    ((uint4*)lds)[s] = pk;
  }

  const int c = cgp * 16 + p;                 // this lane's output column
  const float al = 1.0f / tau[c];
  const float onem = 1.0f - al;
  const float bh_c = b_h[c];
  const float h0c = fminf(1.0f, fmaxf(-1.0f, h0[c]));
  float hprev[4] = {h0c, h0c, h0c, h0c};
  const int rbase = bhh * 32 + wave * 16;     // batch row base of this wave's m-tile

  // one-time: W_uh B-fragments (K=256 -> 8 kb) into registers
  uint4 wu[8];
#pragma unroll
  for (int kb = 0; kb < 8; ++kb) {
    unsigned short v[8];
#pragma unroll
    for (int j = 0; j < 8; ++j)
      v[j] = f2bf(Wuh[(size_t)(kb * 32 + q * 8 + j) * NH + c]);
    wu[kb].x = v[0] | ((unsigned)v[1] << 16);
    wu[kb].y = v[2] | ((unsigned)v[3] << 16);
    wu[kb].z = v[4] | ((unsigned)v[5] << 16);
    wu[kb].w = v[6] | ((unsigned)v[7] << 16);
  }

  // init H[0] (each lane writes its 4 C/D slots)
  unsigned short h0b = f2bf(h0c);
#pragma unroll
  for (int r = 0; r < 4; ++r) H[(size_t)(rbase + q * 4 + r) * NH + c] = h0b;

  cg::grid_group grid = cg::this_grid();
  __threadfence();
  grid.sync();

  const uint4* ldsv = (const uint4*)lds;
  for (int t = 0; t < TT; ++t) {
    f32x4 acc0 = {0.f, 0.f, 0.f, 0.f}, acc1 = acc0, acc2 = acc0, acc3 = acc0;

    // input drive: A-frags from ut (row = t*64 + batch), B-frags in registers
    const uint4* Au = (const uint4*)(ut + ((size_t)t * BB + rbase + p) * N_INP + q * 8);
#pragma unroll
    for (int kb = 0; kb < 8; kb += 4) {
      acc0 = mfma16(Au[(kb + 0) * 4], wu[kb + 0], acc0);
      acc1 = mfma16(Au[(kb + 1) * 4], wu[kb + 1], acc1);
      acc2 = mfma16(Au[(kb + 2) * 4], wu[kb + 2], acc2);
      acc3 = mfma16(Au[(kb + 3) * 4], wu[kb + 3], acc3);
    }

    // recurrent part: A-frags from H[t], B-frags from LDS
    const uint4* Ar = (const uint4*)(H + (size_t)t * BB * NH + (size_t)(rbase + p) * NH + q * 8);
#pragma unroll 4
    for (int kb = 0; kb < 64; kb += 4) {
      uint4 a0 = Ar[(kb + 0) * 4];
      uint4 a1 = Ar[(kb + 1) * 4];
      uint4 a2 = Ar[(kb + 2) * 4];
      uint4 a3 = Ar[(kb + 3) * 4];
      uint4 b0 = ldsv[(kb + 0) * 64 + lane];
      uint4 b1 = ldsv[(kb + 1) * 64 + lane];
      uint4 b2 = ldsv[(kb + 2) * 64 + lane];
      uint4 b3 = ldsv[(kb + 3) * 64 + lane];
      acc0 = mfma16(a0, b0, acc0);
      acc1 = mfma16(a1, b1, acc1);
      acc2 = mfma16(a2, b2, acc2);
      acc3 = mfma16(a3, b3, acc3);
    }

    unsigned short* Hn = H + (size_t)(t + 1) * BB * NH;
#pragma unroll
    for (int r = 0; r < 4; ++r) {
      float pre = acc0[r] + acc1[r] + acc2[r] + acc3[r] + bh_c;
      float hn = onem * hprev[r] + al * fast_tanh(pre);
      hprev[r] = hn;
      Hn[(size_t)(rbase + q * 4 + r) * NH + c] = f2bf(hn);
    }
    __threadfence();
    grid.sync();
  }
}

// ---------------- phase 2: Y = softmax(H[1..T] @ W_hy + b_y) -----------------
// 512 WGs x 256 thr; WG = 64 rows (wave = 16), N = 256 (16 n-tiles)
__global__ __launch_bounds__(256) void k_y(
    const unsigned short* __restrict__ H, const unsigned short* __restrict__ Wyf,
    const float* __restrict__ b_y, float* __restrict__ out) {
  int wave = threadIdx.x >> 6, lane = threadIdx.x & 63;
  int q = lane >> 4, p = lane & 15;
  int R = blockIdx.x * 64 + wave * 16;          // row = t*64+b
  const uint4* A = (const uint4*)(H + (size_t)(R + BB + p) * NH + q * 8);  // +BB: skip H[0]
  const uint4* Bf = (const uint4*)Wyf;
  f32x4 acc[16];
#pragma unroll
  for (int nt = 0; nt < 16; ++nt) acc[nt] = (f32x4){0.f, 0.f, 0.f, 0.f};
  for (int kb = 0; kb < 64; ++kb) {
    uint4 a = A[kb * 4];
#pragma unroll
    for (int nt = 0; nt < 16; ++nt) {
      uint4 b = Bf[(size_t)(kb * 16 + nt) * 64 + lane];
      acc[nt] = mfma16(a, b, acc[nt]);
    }
  }
  float bb[16];
#pragma unroll
  for (int nt = 0; nt < 16; ++nt) bb[nt] = b_y[nt * 16 + p];
#pragma unroll
  for (int r = 0; r < 4; ++r) {
    int row = R + q * 4 + r;
    int tI = row >> 6, bI = row & 63;
    float lg[16];
    float mx = -1e30f;
#pragma unroll
    for (int nt = 0; nt < 16; ++nt) { lg[nt] = acc[nt][r] + bb[nt]; mx = fmaxf(mx, lg[nt]); }
#pragma unroll
    for (int d = 1; d < 16; d <<= 1) mx = fmaxf(mx, __shfl_xor(mx, d));
    float s = 0.f;
#pragma unroll
    for (int nt = 0; nt < 16; ++nt) { lg[nt] = __expf(lg[nt] - mx); s += lg[nt]; }
#pragma unroll
    for (int d = 1; d < 16; d <<= 1) s += __shfl_xor(s, d);
    float inv = 1.0f / s;
    float* orow = out + ((size_t)bI * TT + tI) * NOUT;
#pragma unroll
    for (int nt = 0; nt < 16; ++nt) orow[nt * 16 + p] = lg[nt] * inv;
  }
}

extern "C" void kernel_launch(void* const* d_in, const int* in_sizes, int n_in,
                              void* d_out, int out_size, void* d_ws, size_t ws_size,
                              hipStream_t stream) {
  (void)in_sizes; (void)n_in; (void)out_size; (void)ws_size;
  const float* u   = (const float*)d_in[0];
  const float* Wuh = (const float*)d_in[1];
  const float* Whh = (const float*)d_in[2];
  const float* Why = (const float*)d_in[3];
  const float* b_h = (const float*)d_in[4];
  const float* b_y = (const float*)d_in[5];
  const float* h0  = (const float*)d_in[6];
  const float* tau = (const float*)d_in[7];
  float* out = (float*)d_out;

  char* ws = (char*)d_ws;
  unsigned short* H = (unsigned short*)ws;                       // (T+1)*64*2048 bf16
  size_t off = (size_t)(TT + 1) * BB * NH * 2;                   // 134,479,872
  unsigned short* ut = (unsigned short*)(ws + off);              // T*64*256 bf16
  off += (size_t)TT * BB * N_INP * 2;                            // +16,777,216
  unsigned short* Wyf = (unsigned short*)(ws + off);             // 2048*256 bf16 frags

  k_ut<<<dim3(8192), dim3(256), 0, stream>>>(u, ut);
  k_swz<<<dim3((NH / 32) * (NOUT / 16)), dim3(64), 0, stream>>>(Why, Wyf, NOUT);

  void* args[] = {(void*)&Whh, (void*)&Wuh, (void*)&b_h, (void*)&tau,
                  (void*)&h0, (void*)&ut, (void*)&H};
  hipLaunchCooperativeKernel((const void*)k_step, dim3(256), dim3(128), args, 0, stream);

  k_y<<<dim3(512), dim3(256), 0, stream>>>(H, Wyf, b_y, out);
}

// Round 2
// 9112.453 us; speedup vs baseline: 2.8465x; 2.8465x over previous
//
#include <hip/hip_runtime.h>
#include <hip/hip_fp16.h>

#define N_INP 256
#define NH    2048
#define NOUT  256
#define BB    64
#define TT    512
#define GRIDN 128          // k_step workgroups
#define CNT_STRIDE 16      // uints between barrier counters (64B)

typedef __bf16 bf16x8 __attribute__((ext_vector_type(8)));
typedef float  f32x4  __attribute__((ext_vector_type(4)));

__device__ __forceinline__ unsigned short f2bf(float f) {
  unsigned u = __float_as_uint(f);
  u += 0x7fffu + ((u >> 16) & 1u);          // RTNE
  return (unsigned short)(u >> 16);
}

__device__ __forceinline__ float fast_tanh(float x) {
  x = fminf(9.0f, fmaxf(-9.0f, x));
  float e = __expf(2.0f * x);
  return (e - 1.0f) / (e + 1.0f);
}

__device__ __forceinline__ f32x4 mfma16(uint4 a, uint4 b, f32x4 c) {
  return __builtin_amdgcn_mfma_f32_16x16x32_bf16(
      __builtin_bit_cast(bf16x8, a), __builtin_bit_cast(bf16x8, b), c, 0, 0, 0);
}

// Lightweight grid barrier: unique pre-zeroed counter per step (no reset/ABA).
__device__ __forceinline__ void gbar(unsigned* cnt, int idx) {
  __syncthreads();
  if (threadIdx.x == 0) {
    unsigned* c = cnt + (size_t)idx * CNT_STRIDE;
    __hip_atomic_fetch_add(c, 1u, __ATOMIC_RELEASE, __HIP_MEMORY_SCOPE_AGENT);
    while (__hip_atomic_load(c, __ATOMIC_RELAXED, __HIP_MEMORY_SCOPE_AGENT) < GRIDN)
      __builtin_amdgcn_s_sleep(1);
  }
  __syncthreads();
  __builtin_amdgcn_fence(__ATOMIC_ACQUIRE, "agent");
}

// ---------------- prep: zero barrier counters ----------------
__global__ void k_zero(unsigned* __restrict__ cnt, int n) {
  int i = blockIdx.x * 256 + threadIdx.x;
  if (i < n) cnt[i] = 0;
}

// ---------------- prep: u (B,T,256) f32 -> ut (T*B, 256) bf16 ----------------
__global__ void k_ut(const float* __restrict__ u, unsigned short* __restrict__ ut) {
  int idx = blockIdx.x * 256 + threadIdx.x;    // over 64*512*64 float4 units
  int k4 = idx & 63;
  int rowbt = idx >> 6;                        // row = t*64+b
  int t = rowbt >> 6, b = rowbt & 63;
  float4 f = *(const float4*)(u + ((size_t)b * TT + t) * N_INP + k4 * 4);
  uint2 pk;
  pk.x = f2bf(f.x) | ((unsigned)f2bf(f.y) << 16);
  pk.y = f2bf(f.z) | ((unsigned)f2bf(f.w) << 16);
  *(uint2*)(ut + (size_t)rowbt * N_INP + k4 * 4) = pk;
}

// ------------- prep: W (K,N) f32 row-major -> B-fragment-ordered bf16 --------
// Wf layout: [kb][nt][lane][8], blockIdx.x = kb*(N/16)+nt
__global__ void k_swz(const float* __restrict__ W, unsigned short* __restrict__ Wf, int N) {
  int lane = threadIdx.x;
  int nt16 = N >> 4;
  int kb = blockIdx.x / nt16;
  int nt = blockIdx.x - kb * nt16;
  int k0 = kb * 32 + ((lane >> 4) << 3);
  int c  = nt * 16 + (lane & 15);
  unsigned short v[8];
#pragma unroll
  for (int j = 0; j < 8; ++j) v[j] = f2bf(W[(size_t)(k0 + j) * N + c]);
  uint4 p;
  p.x = v[0] | ((unsigned)v[1] << 16);
  p.y = v[2] | ((unsigned)v[3] << 16);
  p.z = v[4] | ((unsigned)v[5] << 16);
  p.w = v[6] | ((unsigned)v[7] << 16);
  ((uint4*)Wf)[(size_t)blockIdx.x * 64 + lane] = p;
}

// ---------------- persistent recurrence kernel (cooperative) -----------------
// 128 WGs x 256 threads. WG cgp owns columns [cgp*16, cgp*16+16) for ALL 64
// batch rows; wave w = m-tile (rows 16w..16w+16). W_hh column slice resident
// in 64 KiB LDS (B-fragment order) for all 512 steps.
__global__ __launch_bounds__(256) void k_step(
    const float* __restrict__ Whh, const float* __restrict__ Wuh,
    const float* __restrict__ b_h, const float* __restrict__ tau,
    const float* __restrict__ h0, const unsigned short* __restrict__ ut,
    unsigned short* __restrict__ H, unsigned* __restrict__ cnt) {
  __shared__ unsigned short lds[64 * 64 * 8];     // 65536 B: [kb][lane][8]
  const int cgp = blockIdx.x;       // colgroup 0..127
  const int tid = threadIdx.x;
  const int wave = tid >> 6;        // m-tile 0..3
  const int lane = tid & 63;
  const int q = lane >> 4, p = lane & 15;

  // one-time: stage W_hh slice into LDS in B-fragment order
  for (int s = tid; s < 64 * 64; s += 256) {
    int kb = s >> 6, l = s & 63;
    int k0 = kb * 32 + ((l >> 4) << 3);
    int c = cgp * 16 + (l & 15);
    unsigned short v[8];
#pragma unroll
    for (int j = 0; j < 8; ++j) v[j] = f2bf(Whh[(size_t)(k0 + j) * NH + c]);
    uint4 pk;
    pk.x = v[0] | ((unsigned)v[1] << 16);
    pk.y = v[2] | ((unsigned)v[3] << 16);
    pk.z = v[4] | ((unsigned)v[5] << 16);
    pk.w = v[6] | ((unsigned)v[7] << 16);
    ((uint4*)lds)[s] = pk;
  }

  const int c = cgp * 16 + p;                 // this lane's output column
  const float al = 1.0f / tau[c];
  const float onem = 1.0f - al;
  const float bh_c = b_h[c];
  const float h0c = fminf(1.0f, fmaxf(-1.0f, h0[c]));
  float hprev[4] = {h0c, h0c, h0c, h0c};
  const int rbase = wave * 16;                // batch-row base of this wave's m-tile

  // one-time: W_uh B-fragments (K=256 -> 8 kb) into registers
  uint4 wu[8];
#pragma unroll
  for (int kb = 0; kb < 8; ++kb) {
    unsigned short v[8];
#pragma unroll
    for (int j = 0; j < 8; ++j)
      v[j] = f2bf(Wuh[(size_t)(kb * 32 + q * 8 + j) * NH + c]);
    wu[kb].x = v[0] | ((unsigned)v[1] << 16);
    wu[kb].y = v[2] | ((unsigned)v[3] << 16);
    wu[kb].z = v[4] | ((unsigned)v[5] << 16);
    wu[kb].w = v[6] | ((unsigned)v[7] << 16);
  }

  // init H[0] (each lane writes its 4 C/D slots for its m-tile)
  unsigned short h0b = f2bf(h0c);
#pragma unroll
  for (int r = 0; r < 4; ++r) H[(size_t)(rbase + q * 4 + r) * NH + c] = h0b;

  gbar(cnt, 0);

  const uint4* ldsv = (const uint4*)lds;
  for (int t = 0; t < TT; ++t) {
    f32x4 acc[4];
#pragma unroll
    for (int j = 0; j < 4; ++j) acc[j] = (f32x4){0.f, 0.f, 0.f, 0.f};

    // input drive: A-frags from ut (row = t*64 + batch), B-frags in registers
    const uint4* Au = (const uint4*)(ut + ((size_t)t * BB + rbase + p) * N_INP + q * 8);
#pragma unroll
    for (int kb = 0; kb < 8; ++kb)
      acc[kb & 3] = mfma16(Au[kb * 4], wu[kb], acc[kb & 3]);

    // recurrent part: A-frags from H[t] (depth-8 pipelined), B-frags from LDS
    const uint4* Ar = (const uint4*)(H + (size_t)t * BB * NH + (size_t)(rbase + p) * NH + q * 8);
    uint4 a[8];
#pragma unroll
    for (int j = 0; j < 8; ++j) a[j] = Ar[j * 4];
#pragma unroll
    for (int kb = 0; kb < 64; kb += 8) {
      uint4 an[8];
      if (kb < 56) {
#pragma unroll
        for (int j = 0; j < 8; ++j) an[j] = Ar[(kb + 8 + j) * 4];
      }
#pragma unroll
      for (int j = 0; j < 8; ++j)
        acc[j & 3] = mfma16(a[j], ldsv[(kb + j) * 64 + lane], acc[j & 3]);
      if (kb < 56) {
#pragma unroll
        for (int j = 0; j < 8; ++j) a[j] = an[j];
      }
    }

    unsigned short* Hn = H + (size_t)(t + 1) * BB * NH;
#pragma unroll
    for (int r = 0; r < 4; ++r) {
      float pre = acc[0][r] + acc[1][r] + acc[2][r] + acc[3][r] + bh_c;
      float hn = onem * hprev[r] + al * fast_tanh(pre);
      hprev[r] = hn;
      Hn[(size_t)(rbase + q * 4 + r) * NH + c] = f2bf(hn);
    }
    gbar(cnt, t + 1);
  }
}

// ---------------- phase 2: Y = softmax(H[1..T] @ W_hy + b_y) -----------------
// 512 WGs x 256 thr; WG = 64 rows (wave = 16), N = 256 (16 n-tiles)
__global__ __launch_bounds__(256) void k_y(
    const unsigned short* __restrict__ H, const unsigned short* __restrict__ Wyf,
    const float* __restrict__ b_y, float* __restrict__ out) {
  int wave = threadIdx.x >> 6, lane = threadIdx.x & 63;
  int q = lane >> 4, p = lane & 15;
  int R = blockIdx.x * 64 + wave * 16;          // row = t*64+b
  const uint4* A = (const uint4*)(H + (size_t)(R + BB + p) * NH + q * 8);  // +BB: skip H[0]
  const uint4* Bf = (const uint4*)Wyf;
  f32x4 acc[16];
#pragma unroll
  for (int nt = 0; nt < 16; ++nt) acc[nt] = (f32x4){0.f, 0.f, 0.f, 0.f};
  for (int kb = 0; kb < 64; ++kb) {
    uint4 a = A[kb * 4];
#pragma unroll
    for (int nt = 0; nt < 16; ++nt) {
      uint4 b = Bf[(size_t)(kb * 16 + nt) * 64 + lane];
      acc[nt] = mfma16(a, b, acc[nt]);
    }
  }
  float bb[16];
#pragma unroll
  for (int nt = 0; nt < 16; ++nt) bb[nt] = b_y[nt * 16 + p];
#pragma unroll
  for (int r = 0; r < 4; ++r) {
    int row = R + q * 4 + r;
    int tI = row >> 6, bI = row & 63;
    float lg[16];
    float mx = -1e30f;
#pragma unroll
    for (int nt = 0; nt < 16; ++nt) { lg[nt] = acc[nt][r] + bb[nt]; mx = fmaxf(mx, lg[nt]); }
#pragma unroll
    for (int d = 1; d < 16; d <<= 1) mx = fmaxf(mx, __shfl_xor(mx, d));
    float s = 0.f;
#pragma unroll
    for (int nt = 0; nt < 16; ++nt) { lg[nt] = __expf(lg[nt] - mx); s += lg[nt]; }
#pragma unroll
    for (int d = 1; d < 16; d <<= 1) s += __shfl_xor(s, d);
    float inv = 1.0f / s;
    float* orow = out + ((size_t)bI * TT + tI) * NOUT;
#pragma unroll
    for (int nt = 0; nt < 16; ++nt) orow[nt * 16 + p] = lg[nt] * inv;
  }
}

extern "C" void kernel_launch(void* const* d_in, const int* in_sizes, int n_in,
                              void* d_out, int out_size, void* d_ws, size_t ws_size,
                              hipStream_t stream) {
  (void)in_sizes; (void)n_in; (void)out_size; (void)ws_size;
  const float* u   = (const float*)d_in[0];
  const float* Wuh = (const float*)d_in[1];
  const float* Whh = (const float*)d_in[2];
  const float* Why = (const float*)d_in[3];
  const float* b_h = (const float*)d_in[4];
  const float* b_y = (const float*)d_in[5];
  const float* h0  = (const float*)d_in[6];
  const float* tau = (const float*)d_in[7];
  float* out = (float*)d_out;

  char* ws = (char*)d_ws;
  unsigned short* H = (unsigned short*)ws;                       // (T+1)*64*2048 bf16
  size_t off = (size_t)(TT + 1) * BB * NH * 2;                   // 134,479,872
  unsigned short* ut = (unsigned short*)(ws + off);              // T*64*256 bf16
  off += (size_t)TT * BB * N_INP * 2;                            // +16,777,216
  unsigned short* Wyf = (unsigned short*)(ws + off);             // 2048*256 bf16 frags
  off += (size_t)NH * NOUT * 2;                                  // +1,048,576
  unsigned* cnt = (unsigned*)(ws + off);                         // 513*16 uints

  const int ncnt = (TT + 1) * CNT_STRIDE;
  k_zero<<<dim3((ncnt + 255) / 256), dim3(256), 0, stream>>>(cnt, ncnt);
  k_ut<<<dim3(8192), dim3(256), 0, stream>>>(u, ut);
  k_swz<<<dim3((NH / 32) * (NOUT / 16)), dim3(64), 0, stream>>>(Why, Wyf, NOUT);

  void* args[] = {(void*)&Whh, (void*)&Wuh, (void*)&b_h, (void*)&tau,
                  (void*)&h0, (void*)&ut, (void*)&H, (void*)&cnt};
  hipLaunchCooperativeKernel((const void*)k_step, dim3(GRIDN), dim3(256), args, 0, stream);

  k_y<<<dim3(512), dim3(256), 0, stream>>>(H, Wyf, b_y, out);
}

// Round 3
// 6009.126 us; speedup vs baseline: 4.3165x; 1.5164x over previous
//
#include <hip/hip_runtime.h>
#include <hip/hip_fp16.h>

#define N_INP 256
#define NH    2048
#define NOUT  256
#define BB    64
#define TT    512
#define GRIDN 128          // k_step workgroups
#define CNT_STRIDE 16      // uints between barrier counters (64B)

typedef __bf16 bf16x8 __attribute__((ext_vector_type(8)));
typedef float  f32x4  __attribute__((ext_vector_type(4)));

__device__ __forceinline__ unsigned short f2bf(float f) {
  unsigned u = __float_as_uint(f);
  u += 0x7fffu + ((u >> 16) & 1u);          // RTNE
  return (unsigned short)(u >> 16);
}

__device__ __forceinline__ float fast_tanh(float x) {
  x = fminf(9.0f, fmaxf(-9.0f, x));
  float e = __expf(2.0f * x);
  return (e - 1.0f) / (e + 1.0f);
}

__device__ __forceinline__ f32x4 mfma16(uint4 a, uint4 b, f32x4 c) {
  return __builtin_amdgcn_mfma_f32_16x16x32_bf16(
      __builtin_bit_cast(bf16x8, a), __builtin_bit_cast(bf16x8, b), c, 0, 0, 0);
}

// Fence-free grid barrier. Correctness contract:
//  - all H[t+1] data was stored WRITE-THROUGH (relaxed agent atomic stores, sc1)
//  - s_waitcnt(0) per wave drains those stores to the coherence point
//  - counter ops are agent-scope (bypass local L2), one fresh counter per step
//  - readers use cached loads: safe because every H address is written exactly
//    once per launch and no reader touches its line before this barrier.
// => no buffer_wbl2 / buffer_inv anywhere in the loop.
__device__ __forceinline__ void gbar(unsigned* cnt, int idx) {
  __builtin_amdgcn_s_waitcnt(0);
  __syncthreads();
  if (threadIdx.x == 0) {
    unsigned* c = cnt + (size_t)idx * CNT_STRIDE;
    __hip_atomic_fetch_add(c, 1u, __ATOMIC_RELAXED, __HIP_MEMORY_SCOPE_AGENT);
    while (__hip_atomic_load(c, __ATOMIC_RELAXED, __HIP_MEMORY_SCOPE_AGENT) < GRIDN)
      __builtin_amdgcn_s_sleep(1);
  }
  __syncthreads();
}

// ---------------- prep: zero barrier counters ----------------
__global__ void k_zero(unsigned* __restrict__ cnt, int n) {
  int i = blockIdx.x * 256 + threadIdx.x;
  if (i < n) cnt[i] = 0;
}

// ---------------- prep: u (B,T,256) f32 -> ut (T*B, 256) bf16 ----------------
__global__ void k_ut(const float* __restrict__ u, unsigned short* __restrict__ ut) {
  int idx = blockIdx.x * 256 + threadIdx.x;    // over 64*512*64 float4 units
  int k4 = idx & 63;
  int rowbt = idx >> 6;                        // row = t*64+b
  int t = rowbt >> 6, b = rowbt & 63;
  float4 f = *(const float4*)(u + ((size_t)b * TT + t) * N_INP + k4 * 4);
  uint2 pk;
  pk.x = f2bf(f.x) | ((unsigned)f2bf(f.y) << 16);
  pk.y = f2bf(f.z) | ((unsigned)f2bf(f.w) << 16);
  *(uint2*)(ut + (size_t)rowbt * N_INP + k4 * 4) = pk;
}

// ------------- prep: W (K,N) f32 row-major -> B-fragment-ordered bf16 --------
// Wf layout: [kb][nt][lane][8], blockIdx.x = kb*(N/16)+nt
__global__ void k_swz(const float* __restrict__ W, unsigned short* __restrict__ Wf, int N) {
  int lane = threadIdx.x;
  int nt16 = N >> 4;
  int kb = blockIdx.x / nt16;
  int nt = blockIdx.x - kb * nt16;
  int k0 = kb * 32 + ((lane >> 4) << 3);
  int c  = nt * 16 + (lane & 15);
  unsigned short v[8];
#pragma unroll
  for (int j = 0; j < 8; ++j) v[j] = f2bf(W[(size_t)(k0 + j) * N + c]);
  uint4 p;
  p.x = v[0] | ((unsigned)v[1] << 16);
  p.y = v[2] | ((unsigned)v[3] << 16);
  p.z = v[4] | ((unsigned)v[5] << 16);
  p.w = v[6] | ((unsigned)v[7] << 16);
  ((uint4*)Wf)[(size_t)blockIdx.x * 64 + lane] = p;
}

// ---------------- persistent recurrence kernel (cooperative) -----------------
// 128 WGs x 256 threads. WG cgp owns columns [cgp*16, cgp*16+16) for ALL 64
// batch rows; wave w = m-tile (rows 16w..16w+16). W_hh column slice resident
// in 64 KiB LDS (B-fragment order) for all 512 steps.
__global__ __launch_bounds__(256) void k_step(
    const float* __restrict__ Whh, const float* __restrict__ Wuh,
    const float* __restrict__ b_h, const float* __restrict__ tau,
    const float* __restrict__ h0, const unsigned short* __restrict__ ut,
    unsigned short* __restrict__ H, unsigned* __restrict__ cnt) {
  __shared__ unsigned short lds[64 * 64 * 8];     // 65536 B: [kb][lane][8]
  const int cgp = blockIdx.x;       // colgroup 0..127
  const int tid = threadIdx.x;
  const int wave = tid >> 6;        // m-tile 0..3
  const int lane = tid & 63;
  const int q = lane >> 4, p = lane & 15;

  // one-time: stage W_hh slice into LDS in B-fragment order
  for (int s = tid; s < 64 * 64; s += 256) {
    int kb = s >> 6, l = s & 63;
    int k0 = kb * 32 + ((l >> 4) << 3);
    int c = cgp * 16 + (l & 15);
    unsigned short v[8];
#pragma unroll
    for (int j = 0; j < 8; ++j) v[j] = f2bf(Whh[(size_t)(k0 + j) * NH + c]);
    uint4 pk;
    pk.x = v[0] | ((unsigned)v[1] << 16);
    pk.y = v[2] | ((unsigned)v[3] << 16);
    pk.z = v[4] | ((unsigned)v[5] << 16);
    pk.w = v[6] | ((unsigned)v[7] << 16);
    ((uint4*)lds)[s] = pk;
  }

  const int c = cgp * 16 + p;                 // this lane's output column
  const float al = 1.0f / tau[c];
  const float onem = 1.0f - al;
  const float bh_c = b_h[c];
  const float h0c = fminf(1.0f, fmaxf(-1.0f, h0[c]));
  float hprev[4] = {h0c, h0c, h0c, h0c};
  const int rbase = wave * 16;                // batch-row base of this wave's m-tile
  const bool even = (p & 1) == 0;
  const int halfc = cgp * 8 + (p >> 1);       // dword column for packed stores
  unsigned* H32 = (unsigned*)H;

  // one-time: W_uh B-fragments (K=256 -> 8 kb) into registers
  uint4 wu[8];
#pragma unroll
  for (int kb = 0; kb < 8; ++kb) {
    unsigned short v[8];
#pragma unroll
    for (int j = 0; j < 8; ++j)
      v[j] = f2bf(Wuh[(size_t)(kb * 32 + q * 8 + j) * NH + c]);
    wu[kb].x = v[0] | ((unsigned)v[1] << 16);
    wu[kb].y = v[2] | ((unsigned)v[3] << 16);
    wu[kb].z = v[4] | ((unsigned)v[5] << 16);
    wu[kb].w = v[6] | ((unsigned)v[7] << 16);
  }

  // init H[0]: packed write-through stores (lane pairs share one dword)
  {
    unsigned mine = f2bf(h0c);
    unsigned other = (unsigned)__shfl_xor((int)mine, 1);
    unsigned pk0 = even ? (mine | (other << 16)) : (other | (mine << 16));
    if (even) {
#pragma unroll
      for (int r = 0; r < 4; ++r)
        __hip_atomic_store(H32 + (size_t)(rbase + q * 4 + r) * (NH / 2) + halfc,
                           pk0, __ATOMIC_RELAXED, __HIP_MEMORY_SCOPE_AGENT);
    }
  }

  gbar(cnt, 0);

  const uint4* ldsv = (const uint4*)lds;
  for (int t = 0; t < TT; ++t) {
    f32x4 acc[4];
#pragma unroll
    for (int j = 0; j < 4; ++j) acc[j] = (f32x4){0.f, 0.f, 0.f, 0.f};

    // input drive: A-frags from ut (row = t*64 + batch), B-frags in registers
    const uint4* Au = (const uint4*)(ut + ((size_t)t * BB + rbase + p) * N_INP + q * 8);
#pragma unroll
    for (int kb = 0; kb < 8; ++kb)
      acc[kb & 3] = mfma16(Au[kb * 4], wu[kb], acc[kb & 3]);

    // recurrent part: A-frags from H[t] (depth-8 pipelined), B-frags from LDS
    const uint4* Ar = (const uint4*)(H + (size_t)t * BB * NH + (size_t)(rbase + p) * NH + q * 8);
    uint4 a[8];
#pragma unroll
    for (int j = 0; j < 8; ++j) a[j] = Ar[j * 4];
#pragma unroll
    for (int kb = 0; kb < 64; kb += 8) {
      uint4 an[8];
      if (kb < 56) {
#pragma unroll
        for (int j = 0; j < 8; ++j) an[j] = Ar[(kb + 8 + j) * 4];
      }
#pragma unroll
      for (int j = 0; j < 8; ++j)
        acc[j & 3] = mfma16(a[j], ldsv[(kb + j) * 64 + lane], acc[j & 3]);
      if (kb < 56) {
#pragma unroll
        for (int j = 0; j < 8; ++j) a[j] = an[j];
      }
    }

    unsigned* H32n = H32 + (size_t)(t + 1) * BB * (NH / 2);
#pragma unroll
    for (int r = 0; r < 4; ++r) {
      float pre = acc[0][r] + acc[1][r] + acc[2][r] + acc[3][r] + bh_c;
      float hn = onem * hprev[r] + al * fast_tanh(pre);
      hprev[r] = hn;
      unsigned mine = f2bf(hn);
      unsigned other = (unsigned)__shfl_xor((int)mine, 1);
      unsigned pk = even ? (mine | (other << 16)) : (other | (mine << 16));
      if (even)
        __hip_atomic_store(H32n + (size_t)(rbase + q * 4 + r) * (NH / 2) + halfc,
                           pk, __ATOMIC_RELAXED, __HIP_MEMORY_SCOPE_AGENT);
    }
    gbar(cnt, t + 1);
  }
}

// ---------------- phase 2: Y = softmax(H[1..T] @ W_hy + b_y) -----------------
// 512 WGs x 256 thr; WG = 64 rows (wave = 16), N = 256 (16 n-tiles)
__global__ __launch_bounds__(256) void k_y(
    const unsigned short* __restrict__ H, const unsigned short* __restrict__ Wyf,
    const float* __restrict__ b_y, float* __restrict__ out) {
  int wave = threadIdx.x >> 6, lane = threadIdx.x & 63;
  int q = lane >> 4, p = lane & 15;
  int R = blockIdx.x * 64 + wave * 16;          // row = t*64+b
  const uint4* A = (const uint4*)(H + (size_t)(R + BB + p) * NH + q * 8);  // +BB: skip H[0]
  const uint4* Bf = (const uint4*)Wyf;
  f32x4 acc[16];
#pragma unroll
  for (int nt = 0; nt < 16; ++nt) acc[nt] = (f32x4){0.f, 0.f, 0.f, 0.f};
  for (int kb = 0; kb < 64; ++kb) {
    uint4 a = A[kb * 4];
#pragma unroll
    for (int nt = 0; nt < 16; ++nt) {
      uint4 b = Bf[(size_t)(kb * 16 + nt) * 64 + lane];
      acc[nt] = mfma16(a, b, acc[nt]);
    }
  }
  float bb[16];
#pragma unroll
  for (int nt = 0; nt < 16; ++nt) bb[nt] = b_y[nt * 16 + p];
#pragma unroll
  for (int r = 0; r < 4; ++r) {
    int row = R + q * 4 + r;
    int tI = row >> 6, bI = row & 63;
    float lg[16];
    float mx = -1e30f;
#pragma unroll
    for (int nt = 0; nt < 16; ++nt) { lg[nt] = acc[nt][r] + bb[nt]; mx = fmaxf(mx, lg[nt]); }
#pragma unroll
    for (int d = 1; d < 16; d <<= 1) mx = fmaxf(mx, __shfl_xor(mx, d));
    float s = 0.f;
#pragma unroll
    for (int nt = 0; nt < 16; ++nt) { lg[nt] = __expf(lg[nt] - mx); s += lg[nt]; }
#pragma unroll
    for (int d = 1; d < 16; d <<= 1) s += __shfl_xor(s, d);
    float inv = 1.0f / s;
    float* orow = out + ((size_t)bI * TT + tI) * NOUT;
#pragma unroll
    for (int nt = 0; nt < 16; ++nt) orow[nt * 16 + p] = lg[nt] * inv;
  }
}

extern "C" void kernel_launch(void* const* d_in, const int* in_sizes, int n_in,
                              void* d_out, int out_size, void* d_ws, size_t ws_size,
                              hipStream_t stream) {
  (void)in_sizes; (void)n_in; (void)out_size; (void)ws_size;
  const float* u   = (const float*)d_in[0];
  const float* Wuh = (const float*)d_in[1];
  const float* Whh = (const float*)d_in[2];
  const float* Why = (const float*)d_in[3];
  const float* b_h = (const float*)d_in[4];
  const float* b_y = (const float*)d_in[5];
  const float* h0  = (const float*)d_in[6];
  const float* tau = (const float*)d_in[7];
  float* out = (float*)d_out;

  char* ws = (char*)d_ws;
  unsigned short* H = (unsigned short*)ws;                       // (T+1)*64*2048 bf16
  size_t off = (size_t)(TT + 1) * BB * NH * 2;                   // 134,479,872
  unsigned short* ut = (unsigned short*)(ws + off);              // T*64*256 bf16
  off += (size_t)TT * BB * N_INP * 2;                            // +16,777,216
  unsigned short* Wyf = (unsigned short*)(ws + off);             // 2048*256 bf16 frags
  off += (size_t)NH * NOUT * 2;                                  // +1,048,576
  unsigned* cnt = (unsigned*)(ws + off);                         // 513*16 uints

  const int ncnt = (TT + 1) * CNT_STRIDE;
  k_zero<<<dim3((ncnt + 255) / 256), dim3(256), 0, stream>>>(cnt, ncnt);
  k_ut<<<dim3(8192), dim3(256), 0, stream>>>(u, ut);
  k_swz<<<dim3((NH / 32) * (NOUT / 16)), dim3(64), 0, stream>>>(Why, Wyf, NOUT);

  void* args[] = {(void*)&Whh, (void*)&Wuh, (void*)&b_h, (void*)&tau,
                  (void*)&h0, (void*)&ut, (void*)&H, (void*)&cnt};
  hipLaunchCooperativeKernel((const void*)k_step, dim3(GRIDN), dim3(256), args, 0, stream);

  k_y<<<dim3(512), dim3(256), 0, stream>>>(H, Wyf, b_y, out);
}

// Round 4
// 5286.975 us; speedup vs baseline: 4.9061x; 1.1366x over previous
//
#include <hip/hip_runtime.h>
#include <hip/hip_fp16.h>

#define N_INP 256
#define NH    2048
#define NOUT  256
#define BB    64
#define TT    512
#define GRIDN 128          // k_step workgroups
#define REL_STRIDE 32      // dwords between release copies (128B lines)

typedef __bf16 bf16x8 __attribute__((ext_vector_type(8)));
typedef float  f32x4  __attribute__((ext_vector_type(4)));

__device__ __forceinline__ unsigned short f2bf(float f) {
  unsigned u = __float_as_uint(f);
  u += 0x7fffu + ((u >> 16) & 1u);          // RTNE
  return (unsigned short)(u >> 16);
}

__device__ __forceinline__ float fast_tanh(float x) {
  x = fminf(9.0f, fmaxf(-9.0f, x));
  float e = __expf(2.0f * x);
  return (e - 1.0f) / (e + 1.0f);
}

__device__ __forceinline__ f32x4 mfma16(uint4 a, uint4 b, f32x4 c) {
  return __builtin_amdgcn_mfma_f32_16x16x32_bf16(
      __builtin_bit_cast(bf16x8, a), __builtin_bit_cast(bf16x8, b), c, 0, 0, 0);
}

// ---- contention-free split barrier ------------------------------------------
// arrive: drain own write-through stores, then one flag store per WG (own dword,
// no RMW anywhere). wait: WG0/wave0 polls all 128 flags with ONE coalesced
// wave-load + __all; writes 8 replicated release copies; other WGs poll (tid0
// only) their assigned copy. Per-step flag/release slots: pre-zeroed, no reset.
__device__ __forceinline__ void bar_arrive(unsigned* __restrict__ flags, int s) {
  __builtin_amdgcn_s_waitcnt(0);
  __syncthreads();                     // all waves of this WG have drained stores
  if (blockIdx.x != 0 && threadIdx.x == 0)
    __hip_atomic_store(flags + (size_t)s * GRIDN + blockIdx.x, 1u,
                       __ATOMIC_RELAXED, __HIP_MEMORY_SCOPE_AGENT);
}

__device__ __forceinline__ void bar_wait(unsigned* __restrict__ flags,
                                         unsigned* __restrict__ rel, int s) {
  if (blockIdx.x == 0) {
    int tid = threadIdx.x;
    if (tid < 64) {
      const unsigned* f = flags + (size_t)s * GRIDN;
      for (;;) {
        unsigned a = (tid == 0) ? 1u
            : __hip_atomic_load(f + tid, __ATOMIC_RELAXED, __HIP_MEMORY_SCOPE_AGENT);
        unsigned b = __hip_atomic_load(f + 64 + tid, __ATOMIC_RELAXED,
                                       __HIP_MEMORY_SCOPE_AGENT);
        if (__all(a != 0 && b != 0)) break;
        __builtin_amdgcn_s_sleep(1);
      }
      if (tid < 8)
        __hip_atomic_store(rel + ((size_t)s * 8 + tid) * REL_STRIDE, 1u,
                           __ATOMIC_RELAXED, __HIP_MEMORY_SCOPE_AGENT);
    }
    __syncthreads();
  } else {
    if (threadIdx.x == 0) {
      unsigned* r = rel + ((size_t)s * 8 + (blockIdx.x & 7)) * REL_STRIDE;
      while (!__hip_atomic_load(r, __ATOMIC_RELAXED, __HIP_MEMORY_SCOPE_AGENT))
        __builtin_amdgcn_s_sleep(1);
    }
    __syncthreads();
  }
}

// ---------------- prep: zero barrier flags + release slots ----------------
__global__ void k_zero(unsigned* __restrict__ p, int n) {
  int i = blockIdx.x * 256 + threadIdx.x;
  if (i < n) p[i] = 0;
}

// ---------------- prep: u (B,T,256) f32 -> ut (T*B, 256) bf16 ----------------
__global__ void k_ut(const float* __restrict__ u, unsigned short* __restrict__ ut) {
  int idx = blockIdx.x * 256 + threadIdx.x;    // over 64*512*64 float4 units
  int k4 = idx & 63;
  int rowbt = idx >> 6;                        // row = t*64+b
  int t = rowbt >> 6, b = rowbt & 63;
  float4 f = *(const float4*)(u + ((size_t)b * TT + t) * N_INP + k4 * 4);
  uint2 pk;
  pk.x = f2bf(f.x) | ((unsigned)f2bf(f.y) << 16);
  pk.y = f2bf(f.z) | ((unsigned)f2bf(f.w) << 16);
  *(uint2*)(ut + (size_t)rowbt * N_INP + k4 * 4) = pk;
}

// ------------- prep: W (K,N) f32 row-major -> B-fragment-ordered bf16 --------
// Wf layout: [kb][nt][lane][8], blockIdx.x = kb*(N/16)+nt
__global__ void k_swz(const float* __restrict__ W, unsigned short* __restrict__ Wf, int N) {
  int lane = threadIdx.x;
  int nt16 = N >> 4;
  int kb = blockIdx.x / nt16;
  int nt = blockIdx.x - kb * nt16;
  int k0 = kb * 32 + ((lane >> 4) << 3);
  int c  = nt * 16 + (lane & 15);
  unsigned short v[8];
#pragma unroll
  for (int j = 0; j < 8; ++j) v[j] = f2bf(W[(size_t)(k0 + j) * N + c]);
  uint4 p;
  p.x = v[0] | ((unsigned)v[1] << 16);
  p.y = v[2] | ((unsigned)v[3] << 16);
  p.z = v[4] | ((unsigned)v[5] << 16);
  p.w = v[6] | ((unsigned)v[7] << 16);
  ((uint4*)Wf)[(size_t)blockIdx.x * 64 + lane] = p;
}

// ---------------- persistent recurrence kernel (cooperative) -----------------
// 128 WGs x 256 threads. WG cgp owns columns [cgp*16, cgp*16+16) for ALL 64
// batch rows; wave w = m-tile (rows 16w..16w+16). W_hh column slice resident
// in 64 KiB LDS (B-fragment order) for all 512 steps.
__global__ __launch_bounds__(256) void k_step(
    const float* __restrict__ Whh, const float* __restrict__ Wuh,
    const float* __restrict__ b_h, const float* __restrict__ tau,
    const float* __restrict__ h0, const unsigned short* __restrict__ ut,
    unsigned short* __restrict__ H, unsigned* __restrict__ flags,
    unsigned* __restrict__ rel) {
  __shared__ unsigned short lds[64 * 64 * 8];     // 65536 B: [kb][lane][8]
  const int cgp = blockIdx.x;       // colgroup 0..127
  const int tid = threadIdx.x;
  const int wave = tid >> 6;        // m-tile 0..3
  const int lane = tid & 63;
  const int q = lane >> 4, p = lane & 15;

  // one-time: stage W_hh slice into LDS in B-fragment order
  for (int s = tid; s < 64 * 64; s += 256) {
    int kb = s >> 6, l = s & 63;
    int k0 = kb * 32 + ((l >> 4) << 3);
    int c = cgp * 16 + (l & 15);
    unsigned short v[8];
#pragma unroll
    for (int j = 0; j < 8; ++j) v[j] = f2bf(Whh[(size_t)(k0 + j) * NH + c]);
    uint4 pk;
    pk.x = v[0] | ((unsigned)v[1] << 16);
    pk.y = v[2] | ((unsigned)v[3] << 16);
    pk.z = v[4] | ((unsigned)v[5] << 16);
    pk.w = v[6] | ((unsigned)v[7] << 16);
    ((uint4*)lds)[s] = pk;
  }

  const int c = cgp * 16 + p;                 // this lane's output column
  const float al = 1.0f / tau[c];
  const float onem = 1.0f - al;
  const float bh_c = b_h[c];
  const float h0c = fminf(1.0f, fmaxf(-1.0f, h0[c]));
  float hprev[4] = {h0c, h0c, h0c, h0c};
  const int rbase = wave * 16;                // batch-row base of this wave's m-tile
  const bool even = (p & 1) == 0;
  const int halfc = cgp * 8 + (p >> 1);       // dword column for packed stores
  unsigned* H32 = (unsigned*)H;

  // one-time: W_uh B-fragments (K=256 -> 8 kb) into registers
  uint4 wu[8];
#pragma unroll
  for (int kb = 0; kb < 8; ++kb) {
    unsigned short v[8];
#pragma unroll
    for (int j = 0; j < 8; ++j)
      v[j] = f2bf(Wuh[(size_t)(kb * 32 + q * 8 + j) * NH + c]);
    wu[kb].x = v[0] | ((unsigned)v[1] << 16);
    wu[kb].y = v[2] | ((unsigned)v[3] << 16);
    wu[kb].z = v[4] | ((unsigned)v[5] << 16);
    wu[kb].w = v[6] | ((unsigned)v[7] << 16);
  }

  // init H[0]: packed write-through stores (lane pairs share one dword)
  {
    unsigned mine = f2bf(h0c);
    unsigned other = (unsigned)__shfl_xor((int)mine, 1);
    unsigned pk0 = even ? (mine | (other << 16)) : (other | (mine << 16));
    if (even) {
#pragma unroll
      for (int r = 0; r < 4; ++r)
        __hip_atomic_store(H32 + (size_t)(rbase + q * 4 + r) * (NH / 2) + halfc,
                           pk0, __ATOMIC_RELAXED, __HIP_MEMORY_SCOPE_AGENT);
    }
  }

  const uint4* ldsv = (const uint4*)lds;
  f32x4 acc[4];

  bar_arrive(flags, 0);
  // input drive for t=0 (barrier-independent), overlapped with the wait
  {
    const uint4* Au = (const uint4*)(ut + ((size_t)(rbase + p)) * N_INP + q * 8);
#pragma unroll
    for (int j = 0; j < 4; ++j) acc[j] = (f32x4){0.f, 0.f, 0.f, 0.f};
#pragma unroll
    for (int kb = 0; kb < 8; ++kb)
      acc[kb & 3] = mfma16(Au[kb * 4], wu[kb], acc[kb & 3]);
  }
  bar_wait(flags, rel, 0);

  for (int t = 0; t < TT; ++t) {
    // recurrent part: A-frags from H[t] (depth-8 pipelined), B-frags from LDS
    const uint4* Ar = (const uint4*)(H + (size_t)t * BB * NH + (size_t)(rbase + p) * NH + q * 8);
    uint4 a[8];
#pragma unroll
    for (int j = 0; j < 8; ++j) a[j] = Ar[j * 4];
#pragma unroll
    for (int kb = 0; kb < 64; kb += 8) {
      uint4 an[8];
      if (kb < 56) {
#pragma unroll
        for (int j = 0; j < 8; ++j) an[j] = Ar[(kb + 8 + j) * 4];
      }
#pragma unroll
      for (int j = 0; j < 8; ++j)
        acc[j & 3] = mfma16(a[j], ldsv[(kb + j) * 64 + lane], acc[j & 3]);
      if (kb < 56) {
#pragma unroll
        for (int j = 0; j < 8; ++j) a[j] = an[j];
      }
    }

    // epilogue: leaky update, packed write-through store of H[t+1]
    unsigned* H32n = H32 + (size_t)(t + 1) * BB * (NH / 2);
#pragma unroll
    for (int r = 0; r < 4; ++r) {
      float pre = acc[0][r] + acc[1][r] + acc[2][r] + acc[3][r] + bh_c;
      float hn = onem * hprev[r] + al * fast_tanh(pre);
      hprev[r] = hn;
      unsigned mine = f2bf(hn);
      unsigned other = (unsigned)__shfl_xor((int)mine, 1);
      unsigned pk = even ? (mine | (other << 16)) : (other | (mine << 16));
      if (even)
        __hip_atomic_store(H32n + (size_t)(rbase + q * 4 + r) * (NH / 2) + halfc,
                           pk, __ATOMIC_RELAXED, __HIP_MEMORY_SCOPE_AGENT);
    }

    if (t + 1 < TT) {
      bar_arrive(flags, t + 1);
      // input drive for t+1, overlapped with the wait
      const uint4* Au = (const uint4*)(ut + ((size_t)(t + 1) * BB + rbase + p) * N_INP + q * 8);
#pragma unroll
      for (int j = 0; j < 4; ++j) acc[j] = (f32x4){0.f, 0.f, 0.f, 0.f};
#pragma unroll
      for (int kb = 0; kb < 8; ++kb)
        acc[kb & 3] = mfma16(Au[kb * 4], wu[kb], acc[kb & 3]);
      bar_wait(flags, rel, t + 1);
    }
  }
}

// ---------------- phase 2: Y = softmax(H[1..T] @ W_hy + b_y) -----------------
// 512 WGs x 256 thr; WG = 64 rows (wave = 16), N = 256 (16 n-tiles)
__global__ __launch_bounds__(256) void k_y(
    const unsigned short* __restrict__ H, const unsigned short* __restrict__ Wyf,
    const float* __restrict__ b_y, float* __restrict__ out) {
  int wave = threadIdx.x >> 6, lane = threadIdx.x & 63;
  int q = lane >> 4, p = lane & 15;
  int R = blockIdx.x * 64 + wave * 16;          // row = t*64+b
  const uint4* A = (const uint4*)(H + (size_t)(R + BB + p) * NH + q * 8);  // +BB: skip H[0]
  const uint4* Bf = (const uint4*)Wyf;
  f32x4 acc[16];
#pragma unroll
  for (int nt = 0; nt < 16; ++nt) acc[nt] = (f32x4){0.f, 0.f, 0.f, 0.f};
  for (int kb = 0; kb < 64; ++kb) {
    uint4 a = A[kb * 4];
#pragma unroll
    for (int nt = 0; nt < 16; ++nt) {
      uint4 b = Bf[(size_t)(kb * 16 + nt) * 64 + lane];
      acc[nt] = mfma16(a, b, acc[nt]);
    }
  }
  float bb[16];
#pragma unroll
  for (int nt = 0; nt < 16; ++nt) bb[nt] = b_y[nt * 16 + p];
#pragma unroll
  for (int r = 0; r < 4; ++r) {
    int row = R + q * 4 + r;
    int tI = row >> 6, bI = row & 63;
    float lg[16];
    float mx = -1e30f;
#pragma unroll
    for (int nt = 0; nt < 16; ++nt) { lg[nt] = acc[nt][r] + bb[nt]; mx = fmaxf(mx, lg[nt]); }
#pragma unroll
    for (int d = 1; d < 16; d <<= 1) mx = fmaxf(mx, __shfl_xor(mx, d));
    float s = 0.f;
#pragma unroll
    for (int nt = 0; nt < 16; ++nt) { lg[nt] = __expf(lg[nt] - mx); s += lg[nt]; }
#pragma unroll
    for (int d = 1; d < 16; d <<= 1) s += __shfl_xor(s, d);
    float inv = 1.0f / s;
    float* orow = out + ((size_t)bI * TT + tI) * NOUT;
#pragma unroll
    for (int nt = 0; nt < 16; ++nt) orow[nt * 16 + p] = lg[nt] * inv;
  }
}

extern "C" void kernel_launch(void* const* d_in, const int* in_sizes, int n_in,
                              void* d_out, int out_size, void* d_ws, size_t ws_size,
                              hipStream_t stream) {
  (void)in_sizes; (void)n_in; (void)out_size; (void)ws_size;
  const float* u   = (const float*)d_in[0];
  const float* Wuh = (const float*)d_in[1];
  const float* Whh = (const float*)d_in[2];
  const float* Why = (const float*)d_in[3];
  const float* b_h = (const float*)d_in[4];
  const float* b_y = (const float*)d_in[5];
  const float* h0  = (const float*)d_in[6];
  const float* tau = (const float*)d_in[7];
  float* out = (float*)d_out;

  char* ws = (char*)d_ws;
  unsigned short* H = (unsigned short*)ws;                       // (T+1)*64*2048 bf16
  size_t off = (size_t)(TT + 1) * BB * NH * 2;                   // 134,479,872
  unsigned short* ut = (unsigned short*)(ws + off);              // T*64*256 bf16
  off += (size_t)TT * BB * N_INP * 2;                            // +16,777,216
  unsigned short* Wyf = (unsigned short*)(ws + off);             // 2048*256 bf16 frags
  off += (size_t)NH * NOUT * 2;                                  // +1,048,576
  unsigned* flags = (unsigned*)(ws + off);                       // 513*128 dwords
  off += (size_t)(TT + 1) * GRIDN * 4;                           // +262,656
  unsigned* rel = (unsigned*)(ws + off);                         // 513*8*32 dwords

  const int nz = (TT + 1) * GRIDN + (TT + 1) * 8 * REL_STRIDE;   // flags + rel (contiguous)
  k_zero<<<dim3((nz + 255) / 256), dim3(256), 0, stream>>>(flags, nz);
  k_ut<<<dim3(8192), dim3(256), 0, stream>>>(u, ut);
  k_swz<<<dim3((NH / 32) * (NOUT / 16)), dim3(64), 0, stream>>>(Why, Wyf, NOUT);

  void* args[] = {(void*)&Whh, (void*)&Wuh, (void*)&b_h, (void*)&tau,
                  (void*)&h0, (void*)&ut, (void*)&H, (void*)&flags, (void*)&rel};
  hipLaunchCooperativeKernel((const void*)k_step, dim3(GRIDN), dim3(256), args, 0, stream);

  k_y<<<dim3(512), dim3(256), 0, stream>>>(H, Wyf, b_y, out);
}

// Round 5
// 4870.751 us; speedup vs baseline: 5.3253x; 1.0855x over previous
//
#include <hip/hip_runtime.h>
#include <hip/hip_fp16.h>

#define N_INP 256
#define NH    2048
#define NOUT  256
#define BB    64
#define TT    512
#define GRIDN 128          // k_step workgroups
#define NWAVE (GRIDN * 4)  // per-wave arrival flags per step

typedef __bf16 bf16x8 __attribute__((ext_vector_type(8)));
typedef float  f32x4  __attribute__((ext_vector_type(4)));

__device__ __forceinline__ unsigned short f2bf(float f) {
  unsigned u = __float_as_uint(f);
  u += 0x7fffu + ((u >> 16) & 1u);          // RTNE
  return (unsigned short)(u >> 16);
}

__device__ __forceinline__ float fast_tanh(float x) {
  x = fminf(9.0f, fmaxf(-9.0f, x));
  float e = __expf(2.0f * x);
  return (e - 1.0f) / (e + 1.0f);
}

__device__ __forceinline__ f32x4 mfma16(uint4 a, uint4 b, f32x4 c) {
  return __builtin_amdgcn_mfma_f32_16x16x32_bf16(
      __builtin_bit_cast(bf16x8, a), __builtin_bit_cast(bf16x8, b), c, 0, 0, 0);
}

// ---- one-hop wave barrier ---------------------------------------------------
// arrive (per wave, no __syncthreads): workgroup release fence (= s_waitcnt,
// NO L2 cache ops) drains this wave's write-through H stores, then lane 0
// stores this wave's flag (own dword, fresh slot per step, pre-zeroed).
// wait: wave 0 of each WG polls all 512 flags directly (8 coalesced 256B
// agent-scope loads + __all), then releases sibling waves via a monotonic
// LDS counter. No master WG, no release array, no __syncthreads.
__device__ __forceinline__ void bar_arrive(unsigned* __restrict__ flags, int s,
                                           int waveid, int lane) {
  __builtin_amdgcn_fence(__ATOMIC_RELEASE, "workgroup");  // s_waitcnt only
  if (lane == 0)
    __hip_atomic_store(flags + (size_t)s * NWAVE + waveid, 1u,
                       __ATOMIC_RELAXED, __HIP_MEMORY_SCOPE_AGENT);
}

__device__ __forceinline__ void bar_wait(unsigned* __restrict__ flags, int s,
                                         int wave, int lane, unsigned* bar_cnt) {
  if (wave == 0) {
    const unsigned* f = flags + (size_t)s * NWAVE;
    for (;;) {
      unsigned ok = 1u;
#pragma unroll
      for (int j = 0; j < 8; ++j) {
        unsigned v = __hip_atomic_load(f + j * 64 + lane, __ATOMIC_RELAXED,
                                       __HIP_MEMORY_SCOPE_AGENT);
        ok &= (v != 0u) ? 1u : 0u;
      }
      if (__all(ok)) break;
    }
    __hip_atomic_store(bar_cnt, (unsigned)(s + 1), __ATOMIC_RELAXED,
                       __HIP_MEMORY_SCOPE_WORKGROUP);
  } else {
    while (__hip_atomic_load(bar_cnt, __ATOMIC_RELAXED,
                             __HIP_MEMORY_SCOPE_WORKGROUP) < (unsigned)(s + 1))
      __builtin_amdgcn_s_sleep(1);
  }
  __builtin_amdgcn_fence(__ATOMIC_ACQUIRE, "workgroup");  // compiler ordering
}

// ---------------- prep: zero barrier flags ----------------
__global__ void k_zero(unsigned* __restrict__ p, int n) {
  int i = blockIdx.x * 256 + threadIdx.x;
  if (i < n) p[i] = 0;
}

// ---------------- prep: u (B,T,256) f32 -> ut (T*B, 256) bf16 ----------------
__global__ void k_ut(const float* __restrict__ u, unsigned short* __restrict__ ut) {
  int idx = blockIdx.x * 256 + threadIdx.x;    // over 64*512*64 float4 units
  int k4 = idx & 63;
  int rowbt = idx >> 6;                        // row = t*64+b
  int t = rowbt >> 6, b = rowbt & 63;
  float4 f = *(const float4*)(u + ((size_t)b * TT + t) * N_INP + k4 * 4);
  uint2 pk;
  pk.x = f2bf(f.x) | ((unsigned)f2bf(f.y) << 16);
  pk.y = f2bf(f.z) | ((unsigned)f2bf(f.w) << 16);
  *(uint2*)(ut + (size_t)rowbt * N_INP + k4 * 4) = pk;
}

// ------------- prep: W (K,N) f32 row-major -> B-fragment-ordered bf16 --------
// Wf layout: [kb][nt][lane][8], blockIdx.x = kb*(N/16)+nt
__global__ void k_swz(const float* __restrict__ W, unsigned short* __restrict__ Wf, int N) {
  int lane = threadIdx.x;
  int nt16 = N >> 4;
  int kb = blockIdx.x / nt16;
  int nt = blockIdx.x - kb * nt16;
  int k0 = kb * 32 + ((lane >> 4) << 3);
  int c  = nt * 16 + (lane & 15);
  unsigned short v[8];
#pragma unroll
  for (int j = 0; j < 8; ++j) v[j] = f2bf(W[(size_t)(k0 + j) * N + c]);
  uint4 p;
  p.x = v[0] | ((unsigned)v[1] << 16);
  p.y = v[2] | ((unsigned)v[3] << 16);
  p.z = v[4] | ((unsigned)v[5] << 16);
  p.w = v[6] | ((unsigned)v[7] << 16);
  ((uint4*)Wf)[(size_t)blockIdx.x * 64 + lane] = p;
}

// ---------------- persistent recurrence kernel (cooperative) -----------------
// 128 WGs x 256 threads. WG cgp owns columns [cgp*16, cgp*16+16) for ALL 64
// batch rows; wave w = m-tile (rows 16w..16w+16). W_hh column slice resident
// in 64 KiB LDS (B-fragment order) for all 512 steps.
__global__ __launch_bounds__(256) void k_step(
    const float* __restrict__ Whh, const float* __restrict__ Wuh,
    const float* __restrict__ b_h, const float* __restrict__ tau,
    const float* __restrict__ h0, const unsigned short* __restrict__ ut,
    unsigned short* __restrict__ H, unsigned* __restrict__ flags) {
  __shared__ unsigned short lds[64 * 64 * 8];     // 65536 B: [kb][lane][8]
  __shared__ unsigned bar_cnt;
  const int cgp = blockIdx.x;       // colgroup 0..127
  const int tid = threadIdx.x;
  const int wave = tid >> 6;        // m-tile 0..3
  const int lane = tid & 63;
  const int q = lane >> 4, p = lane & 15;
  const int waveid = cgp * 4 + wave;

  // one-time: stage W_hh slice into LDS in B-fragment order
  for (int s = tid; s < 64 * 64; s += 256) {
    int kb = s >> 6, l = s & 63;
    int k0 = kb * 32 + ((l >> 4) << 3);
    int c = cgp * 16 + (l & 15);
    unsigned short v[8];
#pragma unroll
    for (int j = 0; j < 8; ++j) v[j] = f2bf(Whh[(size_t)(k0 + j) * NH + c]);
    uint4 pk;
    pk.x = v[0] | ((unsigned)v[1] << 16);
    pk.y = v[2] | ((unsigned)v[3] << 16);
    pk.z = v[4] | ((unsigned)v[5] << 16);
    pk.w = v[6] | ((unsigned)v[7] << 16);
    ((uint4*)lds)[s] = pk;
  }
  if (tid == 0) bar_cnt = 0;

  const int c = cgp * 16 + p;                 // this lane's output column
  const float al = 1.0f / tau[c];
  const float onem = 1.0f - al;
  const float bh_c = b_h[c];
  const float h0c = fminf(1.0f, fmaxf(-1.0f, h0[c]));
  float hprev[4] = {h0c, h0c, h0c, h0c};
  const int rbase = wave * 16;                // batch-row base of this wave's m-tile
  const bool even = (p & 1) == 0;
  const int halfc = cgp * 8 + (p >> 1);       // dword column for packed stores
  unsigned* H32 = (unsigned*)H;

  // one-time: W_uh B-fragments (K=256 -> 8 kb) into registers
  uint4 wu[8];
#pragma unroll
  for (int kb = 0; kb < 8; ++kb) {
    unsigned short v[8];
#pragma unroll
    for (int j = 0; j < 8; ++j)
      v[j] = f2bf(Wuh[(size_t)(kb * 32 + q * 8 + j) * NH + c]);
    wu[kb].x = v[0] | ((unsigned)v[1] << 16);
    wu[kb].y = v[2] | ((unsigned)v[3] << 16);
    wu[kb].z = v[4] | ((unsigned)v[5] << 16);
    wu[kb].w = v[6] | ((unsigned)v[7] << 16);
  }

  __syncthreads();   // LDS staging + bar_cnt visible to all waves (once)

  // init H[0]: packed write-through stores (lane pairs share one dword)
  {
    unsigned mine = f2bf(h0c);
    unsigned other = (unsigned)__shfl_xor((int)mine, 1);
    unsigned pk0 = even ? (mine | (other << 16)) : (other | (mine << 16));
    if (even) {
#pragma unroll
      for (int r = 0; r < 4; ++r)
        __hip_atomic_store(H32 + (size_t)(rbase + q * 4 + r) * (NH / 2) + halfc,
                           pk0, __ATOMIC_RELAXED, __HIP_MEMORY_SCOPE_AGENT);
    }
  }

  const uint4* ldsv = (const uint4*)lds;
  f32x4 acc[4];

  bar_arrive(flags, 0, waveid, lane);
  // input drive for t=0 (barrier-independent), overlapped with the wait
  {
    const uint4* Au = (const uint4*)(ut + ((size_t)(rbase + p)) * N_INP + q * 8);
#pragma unroll
    for (int j = 0; j < 4; ++j) acc[j] = (f32x4){0.f, 0.f, 0.f, 0.f};
#pragma unroll
    for (int kb = 0; kb < 8; ++kb)
      acc[kb & 3] = mfma16(Au[kb * 4], wu[kb], acc[kb & 3]);
  }
  bar_wait(flags, 0, wave, lane, &bar_cnt);

  for (int t = 0; t < TT; ++t) {
    // recurrent part: A-frags from H[t] (depth-8 pipelined), B-frags from LDS
    const uint4* Ar = (const uint4*)(H + (size_t)t * BB * NH + (size_t)(rbase + p) * NH + q * 8);
    uint4 a[8];
#pragma unroll
    for (int j = 0; j < 8; ++j) a[j] = Ar[j * 4];
#pragma unroll
    for (int kb = 0; kb < 64; kb += 8) {
      uint4 an[8];
      if (kb < 56) {
#pragma unroll
        for (int j = 0; j < 8; ++j) an[j] = Ar[(kb + 8 + j) * 4];
      }
#pragma unroll
      for (int j = 0; j < 8; ++j)
        acc[j & 3] = mfma16(a[j], ldsv[(kb + j) * 64 + lane], acc[j & 3]);
      if (kb < 56) {
#pragma unroll
        for (int j = 0; j < 8; ++j) a[j] = an[j];
      }
    }

    // epilogue: leaky update, packed write-through store of H[t+1]
    unsigned* H32n = H32 + (size_t)(t + 1) * BB * (NH / 2);
#pragma unroll
    for (int r = 0; r < 4; ++r) {
      float pre = acc[0][r] + acc[1][r] + acc[2][r] + acc[3][r] + bh_c;
      float hn = onem * hprev[r] + al * fast_tanh(pre);
      hprev[r] = hn;
      unsigned mine = f2bf(hn);
      unsigned other = (unsigned)__shfl_xor((int)mine, 1);
      unsigned pk = even ? (mine | (other << 16)) : (other | (mine << 16));
      if (even)
        __hip_atomic_store(H32n + (size_t)(rbase + q * 4 + r) * (NH / 2) + halfc,
                           pk, __ATOMIC_RELAXED, __HIP_MEMORY_SCOPE_AGENT);
    }

    if (t + 1 < TT) {
      bar_arrive(flags, t + 1, waveid, lane);
      // input drive for t+1, overlapped with the wait
      const uint4* Au = (const uint4*)(ut + ((size_t)(t + 1) * BB + rbase + p) * N_INP + q * 8);
#pragma unroll
      for (int j = 0; j < 4; ++j) acc[j] = (f32x4){0.f, 0.f, 0.f, 0.f};
#pragma unroll
      for (int kb = 0; kb < 8; ++kb)
        acc[kb & 3] = mfma16(Au[kb * 4], wu[kb], acc[kb & 3]);
      bar_wait(flags, t + 1, wave, lane, &bar_cnt);
    }
  }
}

// ---------------- phase 2: Y = softmax(H[1..T] @ W_hy + b_y) -----------------
// 512 WGs x 256 thr; WG = 64 rows (wave = 16), N = 256 (16 n-tiles)
__global__ __launch_bounds__(256) void k_y(
    const unsigned short* __restrict__ H, const unsigned short* __restrict__ Wyf,
    const float* __restrict__ b_y, float* __restrict__ out) {
  int wave = threadIdx.x >> 6, lane = threadIdx.x & 63;
  int q = lane >> 4, p = lane & 15;
  int R = blockIdx.x * 64 + wave * 16;          // row = t*64+b
  const uint4* A = (const uint4*)(H + (size_t)(R + BB + p) * NH + q * 8);  // +BB: skip H[0]
  const uint4* Bf = (const uint4*)Wyf;
  f32x4 acc[16];
#pragma unroll
  for (int nt = 0; nt < 16; ++nt) acc[nt] = (f32x4){0.f, 0.f, 0.f, 0.f};
  for (int kb = 0; kb < 64; ++kb) {
    uint4 a = A[kb * 4];
#pragma unroll
    for (int nt = 0; nt < 16; ++nt) {
      uint4 b = Bf[(size_t)(kb * 16 + nt) * 64 + lane];
      acc[nt] = mfma16(a, b, acc[nt]);
    }
  }
  float bb[16];
#pragma unroll
  for (int nt = 0; nt < 16; ++nt) bb[nt] = b_y[nt * 16 + p];
#pragma unroll
  for (int r = 0; r < 4; ++r) {
    int row = R + q * 4 + r;
    int tI = row >> 6, bI = row & 63;
    float lg[16];
    float mx = -1e30f;
#pragma unroll
    for (int nt = 0; nt < 16; ++nt) { lg[nt] = acc[nt][r] + bb[nt]; mx = fmaxf(mx, lg[nt]); }
#pragma unroll
    for (int d = 1; d < 16; d <<= 1) mx = fmaxf(mx, __shfl_xor(mx, d));
    float s = 0.f;
#pragma unroll
    for (int nt = 0; nt < 16; ++nt) { lg[nt] = __expf(lg[nt] - mx); s += lg[nt]; }
#pragma unroll
    for (int d = 1; d < 16; d <<= 1) s += __shfl_xor(s, d);
    float inv = 1.0f / s;
    float* orow = out + ((size_t)bI * TT + tI) * NOUT;
#pragma unroll
    for (int nt = 0; nt < 16; ++nt) orow[nt * 16 + p] = lg[nt] * inv;
  }
}

extern "C" void kernel_launch(void* const* d_in, const int* in_sizes, int n_in,
                              void* d_out, int out_size, void* d_ws, size_t ws_size,
                              hipStream_t stream) {
  (void)in_sizes; (void)n_in; (void)out_size; (void)ws_size;
  const float* u   = (const float*)d_in[0];
  const float* Wuh = (const float*)d_in[1];
  const float* Whh = (const float*)d_in[2];
  const float* Why = (const float*)d_in[3];
  const float* b_h = (const float*)d_in[4];
  const float* b_y = (const float*)d_in[5];
  const float* h0  = (const float*)d_in[6];
  const float* tau = (const float*)d_in[7];
  float* out = (float*)d_out;

  char* ws = (char*)d_ws;
  unsigned short* H = (unsigned short*)ws;                       // (T+1)*64*2048 bf16
  size_t off = (size_t)(TT + 1) * BB * NH * 2;                   // 134,479,872
  unsigned short* ut = (unsigned short*)(ws + off);              // T*64*256 bf16
  off += (size_t)TT * BB * N_INP * 2;                            // +16,777,216
  unsigned short* Wyf = (unsigned short*)(ws + off);             // 2048*256 bf16 frags
  off += (size_t)NH * NOUT * 2;                                  // +1,048,576
  unsigned* flags = (unsigned*)(ws + off);                       // 513*512 dwords

  const int nz = (TT + 1) * NWAVE;
  k_zero<<<dim3((nz + 255) / 256), dim3(256), 0, stream>>>(flags, nz);
  k_ut<<<dim3(8192), dim3(256), 0, stream>>>(u, ut);
  k_swz<<<dim3((NH / 32) * (NOUT / 16)), dim3(64), 0, stream>>>(Why, Wyf, NOUT);

  void* args[] = {(void*)&Whh, (void*)&Wuh, (void*)&b_h, (void*)&tau,
                  (void*)&h0, (void*)&ut, (void*)&H, (void*)&flags};
  hipLaunchCooperativeKernel((const void*)k_step, dim3(GRIDN), dim3(256), args, 0, stream);

  k_y<<<dim3(512), dim3(256), 0, stream>>>(H, Wyf, b_y, out);
}